// Round 10
// baseline (410.865 us; speedup 1.0000x reference)
//
#include <hip/hip_runtime.h>
#include <math.h>

#define B 128
#define N 512
#define M 512
#define D 128

typedef __attribute__((ext_vector_type(8))) short s16x8;
typedef __attribute__((ext_vector_type(4))) short s16x4;
typedef __attribute__((ext_vector_type(4))) float f32x4;

#define MFMA16(a, b, c) __builtin_amdgcn_mfma_f32_16x16x32_bf16(a, b, c, 0, 0, 0)

#define VMCNT0()  asm volatile("s_waitcnt vmcnt(0)" ::: "memory")
#define VMCNT4()  asm volatile("s_waitcnt vmcnt(4)" ::: "memory")
#define VMCNT8()  asm volatile("s_waitcnt vmcnt(8)" ::: "memory")
#define VMCNT12() asm volatile("s_waitcnt vmcnt(12)" ::: "memory")

__device__ __forceinline__ void gload16(const void* g, void* l) {
    __builtin_amdgcn_global_load_lds(
        (const __attribute__((address_space(1))) unsigned int*)g,
        (__attribute__((address_space(3))) unsigned int*)l, 16, 0, 0);
}

__device__ __forceinline__ float fast_tanh(float x) {
    x = fminf(fmaxf(x, -15.f), 15.f);
    float E = __expf(2.f * x);
    return 1.f - 2.f / (E + 1.f);
}

// bf16 round-to-nearest-even (unbiased; bias cancellation in num/den ratio)
__device__ __forceinline__ unsigned short bf16rne(float x) {
    unsigned u = __float_as_uint(x);
    return (unsigned short)((u + 0x7FFF + ((u >> 16) & 1)) >> 16);
}

// Truncation split: x ~= hi + lo
__device__ __forceinline__ void fsplit(float x, short& h, short& l) {
    unsigned u = __float_as_uint(x);
    h = (short)(u >> 16);
    float fh = __uint_as_float(u & 0xffff0000u);
    l = (short)(__float_as_uint(x - fh) >> 16);
}

__device__ __forceinline__ void fsplit8(float4 x0, float4 x1, s16x8& h, s16x8& l) {
    short a, b;
    fsplit(x0.x, a, b); h[0] = a; l[0] = b;
    fsplit(x0.y, a, b); h[1] = a; l[1] = b;
    fsplit(x0.z, a, b); h[2] = a; l[2] = b;
    fsplit(x0.w, a, b); h[3] = a; l[3] = b;
    fsplit(x1.x, a, b); h[4] = a; l[4] = b;
    fsplit(x1.y, a, b); h[5] = a; l[5] = b;
    fsplit(x1.z, a, b); h[6] = a; l[6] = b;
    fsplit(x1.w, a, b); h[7] = a; l[7] = b;
}

// EB = exp(-a1ls*cd + ninf) for 8 elements, split to bf16 hi/lo
__device__ __forceinline__ void ebsplit(float4 c0, float4 c1, float4 f0, float4 f1,
                                        float a1ls, s16x8& ah, s16x8& al) {
    float4 e0, e1;
    e0.x = __expf(fmaf(-a1ls, c0.x, f0.x));
    e0.y = __expf(fmaf(-a1ls, c0.y, f0.y));
    e0.z = __expf(fmaf(-a1ls, c0.z, f0.z));
    e0.w = __expf(fmaf(-a1ls, c0.w, f0.w));
    e1.x = __expf(fmaf(-a1ls, c1.x, f1.x));
    e1.y = __expf(fmaf(-a1ls, c1.y, f1.y));
    e1.z = __expf(fmaf(-a1ls, c1.z, f1.z));
    e1.w = __expf(fmaf(-a1ls, c1.w, f1.w));
    fsplit8(e0, e1, ah, al);
}

__global__ void k_prep_w(const float* __restrict__ Wk, const float* __restrict__ Wv,
                         const float* __restrict__ Wq,
                         unsigned short* __restrict__ Wk_hi, unsigned short* __restrict__ Wk_lo,
                         unsigned short* __restrict__ Wv_hi, unsigned short* __restrict__ Wv_lo,
                         unsigned short* __restrict__ Wq_hi, unsigned short* __restrict__ Wq_lo) {
    int i = blockIdx.x * 256 + threadIdx.x;  // 0..49151
    short h, l;
    if (i < 16384) {
        fsplit(Wk[i], h, l); Wk_hi[i] = (unsigned short)h; Wk_lo[i] = (unsigned short)l;
    } else if (i < 32768) {
        int j = i - 16384;
        fsplit(Wv[j], h, l); Wv_hi[j] = (unsigned short)h; Wv_lo[j] = (unsigned short)l;
    } else {
        int j = i - 32768; int e = j >> 7, d = j & 127;
        fsplit(Wq[e * 129 + d], h, l); Wq_hi[j] = (unsigned short)h; Wq_lo[j] = (unsigned short)l;
    }
}

// k = enc@Wk^T, v = enc@Wv^T; store bf16-RNE EK, EK*V as [b][e][m],
// SWIZZLED: within each 32-m group, 8-m chunk c stored at c ^ (e&3).
__global__ __launch_bounds__(256) void k_kv(const float* __restrict__ enc,
        const unsigned short* __restrict__ Wk_hi, const unsigned short* __restrict__ Wk_lo,
        const unsigned short* __restrict__ Wv_hi, const unsigned short* __restrict__ Wv_lo,
        unsigned short* __restrict__ EKb, unsigned short* __restrict__ EKVb) {
    int b = blockIdx.y;
    int wave = threadIdx.x >> 6, lane = threadIdx.x & 63;
    int row = lane & 15, kg = lane >> 4;
    int m0 = blockIdx.x * 64 + wave * 16;
    f32x4 acc[16];
#pragma unroll
    for (int i = 0; i < 16; i++) acc[i] = (f32x4)0.f;
    const float* ap = enc + ((size_t)b * M + m0 + row) * D + kg * 8;
#pragma unroll
    for (int ks = 0; ks < 4; ks++) {
        float4 x0 = *(const float4*)(ap + ks * 32);
        float4 x1 = *(const float4*)(ap + ks * 32 + 4);
        s16x8 ah, al;
        fsplit8(x0, x1, ah, al);
        int wb = ks * 32 + kg * 8;
#pragma unroll
        for (int ct = 0; ct < 8; ct++) {
            int e = ct * 16 + row;
            s16x8 bh = *(const s16x8*)(Wk_hi + e * D + wb);
            s16x8 bl = *(const s16x8*)(Wk_lo + e * D + wb);
            acc[ct] = MFMA16(ah, bh, acc[ct]);
            acc[ct] = MFMA16(al, bh, acc[ct]);
            acc[ct] = MFMA16(ah, bl, acc[ct]);
            bh = *(const s16x8*)(Wv_hi + e * D + wb);
            bl = *(const s16x8*)(Wv_lo + e * D + wb);
            acc[8 + ct] = MFMA16(ah, bh, acc[8 + ct]);
            acc[8 + ct] = MFMA16(al, bh, acc[8 + ct]);
            acc[8 + ct] = MFMA16(ah, bl, acc[8 + ct]);
        }
    }
#pragma unroll
    for (int ct = 0; ct < 8; ct++) {
        int e = ct * 16 + row;
        s16x4 kb, vb;
#pragma unroll
        for (int r = 0; r < 4; r++) {
            float ek = __expf(acc[ct][r]);
            float ev = ek * acc[8 + ct][r];
            kb[r] = (short)bf16rne(ek);
            vb[r] = (short)bf16rne(ev);
        }
        int m = m0 + kg * 4;
        int chunk = (m & 31) >> 3;
        int p = chunk ^ (e & 3);
        size_t o = ((size_t)b * D + e) * M + (size_t)(m & ~31) + p * 8 + (m & 7);
        *(s16x4*)(EKb + o) = kb;
        *(s16x4*)(EKVb + o) = vb;
    }
}

// q = [encl, load]@Wq^T; SQ = sigmoid(q) f32 [b][n][e]
__global__ __launch_bounds__(256) void k_q(const float* __restrict__ encl,
        const float* __restrict__ loadv, const float* __restrict__ Wq,
        const unsigned short* __restrict__ Wq_hi, const unsigned short* __restrict__ Wq_lo,
        float* __restrict__ SQ) {
    int b = blockIdx.y;
    int wave = threadIdx.x >> 6, lane = threadIdx.x & 63;
    int row = lane & 15, kg = lane >> 4;
    int n0 = blockIdx.x * 64 + wave * 16;
    f32x4 acc[8];
#pragma unroll
    for (int i = 0; i < 8; i++) acc[i] = (f32x4)0.f;
    const float* ap = encl + ((size_t)b * N + n0 + row) * D + kg * 8;
#pragma unroll
    for (int ks = 0; ks < 4; ks++) {
        float4 x0 = *(const float4*)(ap + ks * 32);
        float4 x1 = *(const float4*)(ap + ks * 32 + 4);
        s16x8 ah, al;
        fsplit8(x0, x1, ah, al);
        int wb = ks * 32 + kg * 8;
#pragma unroll
        for (int ct = 0; ct < 8; ct++) {
            int e = ct * 16 + row;
            s16x8 bh = *(const s16x8*)(Wq_hi + e * D + wb);
            s16x8 bl = *(const s16x8*)(Wq_lo + e * D + wb);
            acc[ct] = MFMA16(ah, bh, acc[ct]);
            acc[ct] = MFMA16(al, bh, acc[ct]);
            acc[ct] = MFMA16(ah, bl, acc[ct]);
        }
    }
#pragma unroll
    for (int r = 0; r < 4; r++) {
        int n = n0 + kg * 4 + r;
        float lv = loadv[(size_t)b * N + n];
        size_t ro = ((size_t)b * N + n) * D;
#pragma unroll
        for (int ct = 0; ct < 8; ct++) {
            int e = ct * 16 + row;
            float q = acc[ct][r] + lv * Wq[e * 129 + 128];
            SQ[ro + e] = 1.f / (1.f + __expf(-q));
        }
    }
}

// num=EB@EKV, den=EB@EK. 32n x 128e blocks (4 waves e-split), 3-buf LDS staging,
// counted vmcnt (12 until tail), A-regs parity-rotated at depth 2. Grid 2048.
__global__ __launch_bounds__(256, 3) void k_numden(
        const float* __restrict__ cd, const float* __restrict__ ninf,
        const unsigned short* __restrict__ EKVb, const unsigned short* __restrict__ EKb,
        float* __restrict__ SQ,
        const float* __restrict__ a1p, const float* __restrict__ lsp) {
    int o = blockIdx.x;
    int xcd = o & 7, j = o >> 3;       // j 0..255
    int b = ((j >> 4) << 3) + xcd;     // 16 b's per XCD
    int nb = j & 15;
    int n0 = nb * 32;
    int w = threadIdx.x >> 6, lane = threadIdx.x & 63;
    int row = lane & 15, kg = lane >> 4;
    __shared__ __align__(16) char lds[3][16384];  // 3-buf x [2 arr][128 e][32 m x 2B]
    float a1ls = a1p[0] * lsp[0];
    const char* gEKV = (const char*)EKVb + (size_t)b * D * M * 2;
    const char* gEK  = (const char*)EKb  + (size_t)b * D * M * 2;
    f32x4 accN[2][2], accD[2][2];      // [n-set][ct]
#pragma unroll
    for (int s = 0; s < 2; s++)
#pragma unroll
        for (int i = 0; i < 2; i++) { accN[s][i] = (f32x4)0.f; accD[s][i] = (f32x4)0.f; }
    const float* cdp0 = cd + ((size_t)b * N + n0 + row) * M + kg * 8;
    const float* nfp0 = ninf + ((size_t)b * N + n0 + row) * M + kg * 8;
    const float* cdp1 = cdp0 + (size_t)16 * M;
    const float* nfp1 = nfp0 + (size_t)16 * M;
    // read base: e = w*32 + ct*16 + row; swizzled chunk ph = kg ^ (row&3)
    int rbase = w * 2048 + row * 64 + ((kg ^ (row & 3)) << 4);

// stage 16 KB: idx = jv*256 + tid in [0,1024); arr=idx>>9, e=(idx>>2)&127, c16=idx&3
#define STAGE_ND(ldsbase, mt)                                                    \
    _Pragma("unroll")                                                            \
    for (int jv = 0; jv < 4; jv++) {                                             \
        int idx = jv * 256 + threadIdx.x;                                        \
        const char* gb = (idx >> 9) ? gEK : gEKV;                                \
        int rem = idx & 511;                                                     \
        gload16(gb + (size_t)(rem >> 2) * 1024 + (size_t)(mt) * 64 + (rem & 3) * 16, \
                (char*)(ldsbase) + idx * 16);                                    \
    }

    // A regs, parity-indexed: [parity][set][half]
    float4 Ac[2][2][2], Af[2][2][2];
#define LOAD_A(p, mt)                                                            \
    Ac[p][0][0] = *(const float4*)(cdp0 + (mt) * 32);                            \
    Ac[p][0][1] = *(const float4*)(cdp0 + (mt) * 32 + 4);                        \
    Af[p][0][0] = *(const float4*)(nfp0 + (mt) * 32);                            \
    Af[p][0][1] = *(const float4*)(nfp0 + (mt) * 32 + 4);                        \
    Ac[p][1][0] = *(const float4*)(cdp1 + (mt) * 32);                            \
    Ac[p][1][1] = *(const float4*)(cdp1 + (mt) * 32 + 4);                        \
    Af[p][1][0] = *(const float4*)(nfp1 + (mt) * 32);                            \
    Af[p][1][1] = *(const float4*)(nfp1 + (mt) * 32 + 4);

    // prologue issue order fixes the vmcnt ledger: A0, S0, A1, S1
    LOAD_A(0, 0)
    STAGE_ND((char*)lds, 0)
    LOAD_A(1, 1)
    STAGE_ND((char*)lds + 16384, 1)

#pragma unroll
    for (int mt = 0; mt < 16; mt++) {
        // 12 youngest at this wait = A(mt+1)[8] + S(mt+1)[4] (issued last phase)
        if (mt == 15) { VMCNT0(); } else { VMCNT12(); }
        __builtin_amdgcn_s_barrier();
        __builtin_amdgcn_sched_barrier(0);
        int p = mt & 1;
        s16x8 ah0, al0, ah1, al1;
        ebsplit(Ac[p][0][0], Ac[p][0][1], Af[p][0][0], Af[p][0][1], a1ls, ah0, al0);
        ebsplit(Ac[p][1][0], Ac[p][1][1], Af[p][1][0], Af[p][1][1], a1ls, ah1, al1);
        // reload freed parity slot for mt+2; stage tile mt+2 (2-phase slack)
        if (mt <= 13) {
            LOAD_A(p, mt + 2)
            STAGE_ND((char*)lds + ((mt + 2) % 3) * 16384, mt + 2)
        }
        const char* L = (const char*)lds + (mt % 3) * 16384;
#pragma unroll
        for (int ct = 0; ct < 2; ct++) {
            int ro = ct * 1024 + rbase;
            s16x8 bv = *(const s16x8*)(L + ro);           // EKV bf16
            s16x8 bk = *(const s16x8*)(L + 8192 + ro);    // EK bf16
            accN[0][ct] = MFMA16(ah0, bv, accN[0][ct]);
            accN[0][ct] = MFMA16(al0, bv, accN[0][ct]);
            accN[1][ct] = MFMA16(ah1, bv, accN[1][ct]);
            accN[1][ct] = MFMA16(al1, bv, accN[1][ct]);
            accD[0][ct] = MFMA16(ah0, bk, accD[0][ct]);
            accD[0][ct] = MFMA16(al0, bk, accD[0][ct]);
            accD[1][ct] = MFMA16(ah1, bk, accD[1][ct]);
            accD[1][ct] = MFMA16(al1, bk, accD[1][ct]);
        }
    }
#pragma unroll
    for (int s = 0; s < 2; s++) {
#pragma unroll
        for (int r = 0; r < 4; r++) {
            int n = n0 + s * 16 + kg * 4 + r;
            size_t ro = ((size_t)b * N + n) * D;
#pragma unroll
            for (int ct = 0; ct < 2; ct++) {
                int e = w * 32 + ct * 16 + row;
                float num = accN[s][ct][r], den = accD[s][ct][r];
                float ww = (den != 0.f) ? num / den : 0.f;
                float aafm = SQ[ro + e] * ww;
                unsigned u = __float_as_uint(aafm);
                unsigned hi = u >> 16;
                float fh = __uint_as_float(u & 0xffff0000u);
                unsigned lo = __float_as_uint(aafm - fh) >> 16;
                SQ[ro + e] = __uint_as_float(hi | (lo << 16));
            }
        }
    }
}

// Split enc -> bf16 hi/lo [b][m][128e], SWIZZLED: 8-e chunk c at c ^ (m&7)
__global__ void k_encsplit(const float* __restrict__ enc,
                           unsigned short* __restrict__ Eh, unsigned short* __restrict__ El) {
    size_t i = (size_t)blockIdx.x * 256 + threadIdx.x;   // chunk id
    size_t bm = i >> 4;
    int c = (int)(i & 15);
    int m = (int)(bm & 511);
    int p = c ^ (m & 7);
    const float* src = enc + bm * 128 + c * 8;
    float4 x0 = *(const float4*)(src);
    float4 x1 = *(const float4*)(src + 4);
    s16x8 h, l;
    fsplit8(x0, x1, h, l);
    *(s16x8*)(Eh + bm * 128 + p * 8) = h;
    *(s16x8*)(El + bm * 128 + p * 8) = l;
}

// score = AAFM@enc^T; triple-buffered staging + counted vmcnt + raw s_barrier;
// cd/ninf register-prefetched 1 phase ahead; in-loop bias+tanh; fused softmax.
// Grid 2048 XCD-bijective, 3 blocks/CU.
__global__ __launch_bounds__(256, 3) void k_score(
        const float* __restrict__ AAFM,
        const unsigned short* __restrict__ Eh, const unsigned short* __restrict__ El,
        const float* __restrict__ cd, const float* __restrict__ ninf,
        const float* __restrict__ a2p, const float* __restrict__ lsp,
        float* __restrict__ out) {
    int o = blockIdx.x;
    int xcd = o & 7, j = o >> 3;       // j 0..255
    int b = ((j >> 4) << 3) + xcd;     // 16 b's per XCD
    int nb = j & 15;
    int n0 = nb * 32;
    int w = threadIdx.x >> 6, lane = threadIdx.x & 63;
    int row = lane & 15, kg = lane >> 4;
    int ng = w >> 1, mh = w & 1;
    __shared__ __align__(16) char lds[3][16384];  // 3-buf x [hi|lo][32 m][256 B]
    __shared__ float redm[32][2];
    __shared__ float reds[32][2];
    float a2ls = a2p[0] * lsp[0];
    const float invs = 0.08838834764831845f;  // 1/sqrt(128)

    // A preload: 16 rows of packed AAFM (hi|lo<<16)
    const float* apk = AAFM + ((size_t)b * N + n0 + ng * 16 + row) * D + kg * 8;
    s16x8 ah[4], al[4];
#pragma unroll
    for (int es = 0; es < 4; es++) {
        float4 w0 = *(const float4*)(apk + es * 32);
        float4 w1 = *(const float4*)(apk + es * 32 + 4);
        unsigned u;
        u = __float_as_uint(w0.x); ah[es][0] = (short)(u & 0xffff); al[es][0] = (short)(u >> 16);
        u = __float_as_uint(w0.y); ah[es][1] = (short)(u & 0xffff); al[es][1] = (short)(u >> 16);
        u = __float_as_uint(w0.z); ah[es][2] = (short)(u & 0xffff); al[es][2] = (short)(u >> 16);
        u = __float_as_uint(w0.w); ah[es][3] = (short)(u & 0xffff); al[es][3] = (short)(u >> 16);
        u = __float_as_uint(w1.x); ah[es][4] = (short)(u & 0xffff); al[es][4] = (short)(u >> 16);
        u = __float_as_uint(w1.y); ah[es][5] = (short)(u & 0xffff); al[es][5] = (short)(u >> 16);
        u = __float_as_uint(w1.z); ah[es][6] = (short)(u & 0xffff); al[es][6] = (short)(u >> 16);
        u = __float_as_uint(w1.w); ah[es][7] = (short)(u & 0xffff); al[es][7] = (short)(u >> 16);
    }
    f32x4 acc[16];
#pragma unroll
    for (int i = 0; i < 16; i++) acc[i] = (f32x4)0.f;

    int mloc = mh * 16 + row;
    int rbase = mloc * 256;
    int sw = mloc & 7;
    size_t rowidx[4];
#pragma unroll
    for (int r = 0; r < 4; r++)
        rowidx[r] = ((size_t)b * N + n0 + ng * 16 + kg * 4 + r) * M;

#define STAGE_SC(ldsbase, mc)                                                      \
    _Pragma("unroll")                                                              \
    for (int jv = 0; jv < 4; jv++) {                                               \
        int id = (w * 4 + jv) * 64 + lane;                                         \
        int arr = id >> 9, rem = id & 511;                                         \
        const unsigned short* gb = arr ? El : Eh;                                  \
        gload16((const char*)gb + ((size_t)b * M + (size_t)(mc) * 32) * 256 + rem * 16, \
                (char*)(ldsbase) + arr * 8192 + rem * 16);                         \
    }

    // prologue: cd/ninf for tile 0, stage tiles 0 and 1
    float cdv[4], nfv[4];
#pragma unroll
    for (int r = 0; r < 4; r++) {
        cdv[r] = cd[rowidx[r] + mloc];
        nfv[r] = ninf[rowidx[r] + mloc];
    }
    STAGE_SC((char*)lds, 0)
    STAGE_SC((char*)lds + 16384, 1)

#pragma unroll
    for (int mc = 0; mc < 16; mc++) {
        // counted waits: younger-than-stage(mc) = cdnf(mc)[8] + stage(mc+1)[4]
        if (mc == 0) { VMCNT4(); } else if (mc == 15) { VMCNT8(); } else { VMCNT12(); }
        __builtin_amdgcn_s_barrier();
        __builtin_amdgcn_sched_barrier(0);
        // issue next tile's cd/ninf loads
        float ncd[4], nnf[4];
        if (mc < 15) {
#pragma unroll
            for (int r = 0; r < 4; r++) {
                ncd[r] = cd[rowidx[r] + (size_t)(mc + 1) * 32 + mloc];
                nnf[r] = ninf[rowidx[r] + (size_t)(mc + 1) * 32 + mloc];
            }
        }
        // stage tile mc+2
        if (mc < 14) STAGE_SC((char*)lds + ((mc + 2) % 3) * 16384, mc + 2)
        const char* L = (const char*)lds + (mc % 3) * 16384;
#pragma unroll
        for (int es = 0; es < 4; es++) {
            int ph = (4 * es + kg) ^ sw;
            s16x8 bh = *(const s16x8*)(L + rbase + ph * 16);
            s16x8 bl = *(const s16x8*)(L + 8192 + rbase + ph * 16);
            acc[mc] = MFMA16(ah[es], bh, acc[mc]);
            acc[mc] = MFMA16(al[es], bh, acc[mc]);
            acc[mc] = MFMA16(ah[es], bl, acc[mc]);
        }
        // bias + tanh + mask with this tile's prefetched cd/ninf
#pragma unroll
        for (int r = 0; r < 4; r++) {
            acc[mc][r] = 10.f * fast_tanh(fmaf(acc[mc][r], invs, -a2ls * cdv[r]))
                       + nfv[r];
        }
        if (mc < 15) {
#pragma unroll
            for (int r = 0; r < 4; r++) { cdv[r] = ncd[r]; nfv[r] = nnf[r]; }
        }
    }
    // softmax over m (cross-wave via mh halves)
    float mx[4], sm[4];
#pragma unroll
    for (int r = 0; r < 4; r++) {
        float m = acc[0][r];
#pragma unroll
        for (int a = 1; a < 16; a++) m = fmaxf(m, acc[a][r]);
#pragma unroll
        for (int s = 1; s < 16; s <<= 1) m = fmaxf(m, __shfl_xor(m, s, 64));
        mx[r] = m;
    }
    int rl = ng * 16 + kg * 4;
    if (row == 0) {
#pragma unroll
        for (int r = 0; r < 4; r++) redm[rl + r][mh] = mx[r];
    }
    __syncthreads();
#pragma unroll
    for (int r = 0; r < 4; r++) {
        float m = fmaxf(redm[rl + r][0], redm[rl + r][1]);
        float s = 0.f;
#pragma unroll
        for (int a = 0; a < 16; a++) {
            float e = __expf(acc[a][r] - m);
            acc[a][r] = e;
            s += e;
        }
#pragma unroll
        for (int sh = 1; sh < 16; sh <<= 1) s += __shfl_xor(s, sh, 64);
        sm[r] = s;
    }
    if (row == 0) {
#pragma unroll
        for (int r = 0; r < 4; r++) reds[rl + r][mh] = sm[r];
    }
    __syncthreads();
#pragma unroll
    for (int r = 0; r < 4; r++) {
        float inv = 1.f / (reds[rl + r][0] + reds[rl + r][1]);
        size_t ro = ((size_t)b * N + n0 + rl + r) * M;
#pragma unroll
        for (int a = 0; a < 16; a++) {
            out[ro + a * 32 + mh * 16 + row] = acc[a][r] * inv;
        }
    }
}

extern "C" void kernel_launch(void* const* d_in, const int* in_sizes, int n_in,
                              void* d_out, int out_size, void* d_ws, size_t ws_size,
                              hipStream_t stream) {
    const float* encl  = (const float*)d_in[0];
    const float* loadv = (const float*)d_in[1];
    const float* cdist = (const float*)d_in[2];
    const float* ls    = (const float*)d_in[3];
    const float* ninf  = (const float*)d_in[4];
    const float* enc   = (const float*)d_in[5];
    const float* Wq    = (const float*)d_in[6];
    const float* Wk    = (const float*)d_in[7];
    const float* Wv    = (const float*)d_in[8];
    const float* a1    = (const float*)d_in[9];
    const float* a2    = (const float*)d_in[10];
    char* ws = (char*)d_ws;
    unsigned short* EKb     = (unsigned short*)(ws);                 // 33.5 MB
    unsigned short* EKVb    = (unsigned short*)(ws + 33554432);      // 33.5 MB
    float*          SQ      = (float*)(ws + 67108864);               // 33.5 MB
    unsigned short* Wk_hi   = (unsigned short*)(ws + 100663296);
    unsigned short* Wk_lo   = (unsigned short*)(ws + 100663296 + 32768);
    unsigned short* Wv_hi   = (unsigned short*)(ws + 100663296 + 65536);
    unsigned short* Wv_lo   = (unsigned short*)(ws + 100663296 + 98304);
    unsigned short* Wq_hi   = (unsigned short*)(ws + 100663296 + 131072);
    unsigned short* Wq_lo   = (unsigned short*)(ws + 100663296 + 163840);
    unsigned short* ENC_hi  = EKb;    // reuse dead EK/EKV regions after k_numden
    unsigned short* ENC_lo  = EKVb;
    float* out = (float*)d_out;

    k_prep_w<<<192, 256, 0, stream>>>(Wk, Wv, Wq, Wk_hi, Wk_lo, Wv_hi, Wv_lo, Wq_hi, Wq_lo);
    k_kv<<<dim3(8, 128), 256, 0, stream>>>(enc, Wk_hi, Wk_lo, Wv_hi, Wv_lo, EKb, EKVb);
    k_q<<<dim3(8, 128), 256, 0, stream>>>(encl, loadv, Wq, Wq_hi, Wq_lo, SQ);
    k_numden<<<2048, 256, 0, stream>>>(cdist, ninf, EKVb, EKb, SQ, a1, ls);
    k_encsplit<<<4096, 256, 0, stream>>>(enc, ENC_hi, ENC_lo);
    k_score<<<2048, 256, 0, stream>>>(SQ, ENC_hi, ENC_lo, cdist, ninf, a2, ls, out);
}

// Round 11
// 363.099 us; speedup vs baseline: 1.1316x; 1.1316x over previous
//
#include <hip/hip_runtime.h>
#include <math.h>

#define B 128
#define N 512
#define M 512
#define D 128

typedef __attribute__((ext_vector_type(8))) short s16x8;
typedef __attribute__((ext_vector_type(4))) short s16x4;
typedef __attribute__((ext_vector_type(4))) float f32x4;

#define MFMA16(a, b, c) __builtin_amdgcn_mfma_f32_16x16x32_bf16(a, b, c, 0, 0, 0)

__device__ __forceinline__ void gload16(const void* g, void* l) {
    __builtin_amdgcn_global_load_lds(
        (const __attribute__((address_space(1))) unsigned int*)g,
        (__attribute__((address_space(3))) unsigned int*)l, 16, 0, 0);
}

__device__ __forceinline__ float fast_tanh(float x) {
    x = fminf(fmaxf(x, -15.f), 15.f);
    float E = __expf(2.f * x);
    return 1.f - 2.f / (E + 1.f);
}

// bf16 round-to-nearest-even (unbiased)
__device__ __forceinline__ unsigned short bf16rne(float x) {
    unsigned u = __float_as_uint(x);
    return (unsigned short)((u + 0x7FFF + ((u >> 16) & 1)) >> 16);
}

// Truncation split: x ~= hi + lo
__device__ __forceinline__ void fsplit(float x, short& h, short& l) {
    unsigned u = __float_as_uint(x);
    h = (short)(u >> 16);
    float fh = __uint_as_float(u & 0xffff0000u);
    l = (short)(__float_as_uint(x - fh) >> 16);
}

__device__ __forceinline__ void fsplit8(float4 x0, float4 x1, s16x8& h, s16x8& l) {
    short a, b;
    fsplit(x0.x, a, b); h[0] = a; l[0] = b;
    fsplit(x0.y, a, b); h[1] = a; l[1] = b;
    fsplit(x0.z, a, b); h[2] = a; l[2] = b;
    fsplit(x0.w, a, b); h[3] = a; l[3] = b;
    fsplit(x1.x, a, b); h[4] = a; l[4] = b;
    fsplit(x1.y, a, b); h[5] = a; l[5] = b;
    fsplit(x1.z, a, b); h[6] = a; l[6] = b;
    fsplit(x1.w, a, b); h[7] = a; l[7] = b;
}

// EB = exp(-a1ls*cd + ninf) for 8 elements -> single bf16 RNE
__device__ __forceinline__ void ebpack(float4 c0, float4 c1, float4 f0, float4 f1,
                                       float a1ls, s16x8& a) {
    a[0] = (short)bf16rne(__expf(fmaf(-a1ls, c0.x, f0.x)));
    a[1] = (short)bf16rne(__expf(fmaf(-a1ls, c0.y, f0.y)));
    a[2] = (short)bf16rne(__expf(fmaf(-a1ls, c0.z, f0.z)));
    a[3] = (short)bf16rne(__expf(fmaf(-a1ls, c0.w, f0.w)));
    a[4] = (short)bf16rne(__expf(fmaf(-a1ls, c1.x, f1.x)));
    a[5] = (short)bf16rne(__expf(fmaf(-a1ls, c1.y, f1.y)));
    a[6] = (short)bf16rne(__expf(fmaf(-a1ls, c1.z, f1.z)));
    a[7] = (short)bf16rne(__expf(fmaf(-a1ls, c1.w, f1.w)));
}

__global__ void k_prep_w(const float* __restrict__ Wk, const float* __restrict__ Wv,
                         const float* __restrict__ Wq,
                         unsigned short* __restrict__ Wk_hi, unsigned short* __restrict__ Wk_lo,
                         unsigned short* __restrict__ Wv_hi, unsigned short* __restrict__ Wv_lo,
                         unsigned short* __restrict__ Wq_hi, unsigned short* __restrict__ Wq_lo) {
    int i = blockIdx.x * 256 + threadIdx.x;  // 0..49151
    short h, l;
    if (i < 16384) {
        fsplit(Wk[i], h, l); Wk_hi[i] = (unsigned short)h; Wk_lo[i] = (unsigned short)l;
    } else if (i < 32768) {
        int j = i - 16384;
        fsplit(Wv[j], h, l); Wv_hi[j] = (unsigned short)h; Wv_lo[j] = (unsigned short)l;
    } else {
        int j = i - 32768; int e = j >> 7, d = j & 127;
        fsplit(Wq[e * 129 + d], h, l); Wq_hi[j] = (unsigned short)h; Wq_lo[j] = (unsigned short)l;
    }
}

// k = enc@Wk^T, v = enc@Wv^T; store bf16-RNE EK, EK*V as [b][e][m],
// SWIZZLED: within each 32-m group, 8-m chunk c stored at c ^ (e&3).
__global__ __launch_bounds__(256) void k_kv(const float* __restrict__ enc,
        const unsigned short* __restrict__ Wk_hi, const unsigned short* __restrict__ Wk_lo,
        const unsigned short* __restrict__ Wv_hi, const unsigned short* __restrict__ Wv_lo,
        unsigned short* __restrict__ EKb, unsigned short* __restrict__ EKVb) {
    int b = blockIdx.y;
    int wave = threadIdx.x >> 6, lane = threadIdx.x & 63;
    int row = lane & 15, kg = lane >> 4;
    int m0 = blockIdx.x * 64 + wave * 16;
    f32x4 acc[16];
#pragma unroll
    for (int i = 0; i < 16; i++) acc[i] = (f32x4)0.f;
    const float* ap = enc + ((size_t)b * M + m0 + row) * D + kg * 8;
#pragma unroll
    for (int ks = 0; ks < 4; ks++) {
        float4 x0 = *(const float4*)(ap + ks * 32);
        float4 x1 = *(const float4*)(ap + ks * 32 + 4);
        s16x8 ah, al;
        fsplit8(x0, x1, ah, al);
        int wb = ks * 32 + kg * 8;
#pragma unroll
        for (int ct = 0; ct < 8; ct++) {
            int e = ct * 16 + row;
            s16x8 bh = *(const s16x8*)(Wk_hi + e * D + wb);
            s16x8 bl = *(const s16x8*)(Wk_lo + e * D + wb);
            acc[ct] = MFMA16(ah, bh, acc[ct]);
            acc[ct] = MFMA16(al, bh, acc[ct]);
            acc[ct] = MFMA16(ah, bl, acc[ct]);
            bh = *(const s16x8*)(Wv_hi + e * D + wb);
            bl = *(const s16x8*)(Wv_lo + e * D + wb);
            acc[8 + ct] = MFMA16(ah, bh, acc[8 + ct]);
            acc[8 + ct] = MFMA16(al, bh, acc[8 + ct]);
            acc[8 + ct] = MFMA16(ah, bl, acc[8 + ct]);
        }
    }
#pragma unroll
    for (int ct = 0; ct < 8; ct++) {
        int e = ct * 16 + row;
        s16x4 kb, vb;
#pragma unroll
        for (int r = 0; r < 4; r++) {
            float ek = __expf(acc[ct][r]);
            float ev = ek * acc[8 + ct][r];
            kb[r] = (short)bf16rne(ek);
            vb[r] = (short)bf16rne(ev);
        }
        int m = m0 + kg * 4;
        int chunk = (m & 31) >> 3;
        int p = chunk ^ (e & 3);
        size_t o = ((size_t)b * D + e) * M + (size_t)(m & ~31) + p * 8 + (m & 7);
        *(s16x4*)(EKb + o) = kb;
        *(s16x4*)(EKVb + o) = vb;
    }
}

// Split enc -> bf16 hi/lo [b][m][128e], SWIZZLED: 8-e chunk c at c ^ (m&7)
__global__ void k_encsplit(const float* __restrict__ enc,
                           unsigned short* __restrict__ Eh, unsigned short* __restrict__ El) {
    size_t i = (size_t)blockIdx.x * 256 + threadIdx.x;   // chunk id
    size_t bm = i >> 4;
    int c = (int)(i & 15);
    int m = (int)(bm & 511);
    int p = c ^ (m & 7);
    const float* src = enc + bm * 128 + c * 8;
    float4 x0 = *(const float4*)(src);
    float4 x1 = *(const float4*)(src + 4);
    s16x8 h, l;
    fsplit8(x0, x1, h, l);
    *(s16x8*)(Eh + bm * 128 + p * 8) = h;
    *(s16x8*)(El + bm * 128 + p * 8) = l;
}

// MEGA-FUSED: q + sigmoid + numden + aafm + score + tanh/mask + softmax.
// Block = (b, 32-row n-tile), 4 waves. Grid 2048 XCD-bijective.
__global__ __launch_bounds__(256, 3) void k_fused(
        const float* __restrict__ encl, const float* __restrict__ loadv,
        const float* __restrict__ Wq,
        const unsigned short* __restrict__ Wq_hi, const unsigned short* __restrict__ Wq_lo,
        const float* __restrict__ cd, const float* __restrict__ ninf,
        const unsigned short* __restrict__ EKVb, const unsigned short* __restrict__ EKb,
        const unsigned short* __restrict__ Eh, const unsigned short* __restrict__ El,
        const float* __restrict__ a1p, const float* __restrict__ a2p,
        const float* __restrict__ lsp, float* __restrict__ out) {
    int o = blockIdx.x;
    int xcd = o & 7, j = o >> 3;       // j 0..255
    int b = ((j >> 4) << 3) + xcd;     // 16 b's per XCD
    int nb = j & 15;
    int n0 = nb * 32;
    int w = threadIdx.x >> 6, lane = threadIdx.x & 63;
    int row = lane & 15, kg = lane >> 4;
    int ng = w >> 1, mh = w & 1;
    __shared__ __align__(16) char lds[2][16384];
    __shared__ float redm[32][2], reds[32][2];
    float a1ls = a1p[0] * lsp[0];
    float a2ls = a2p[0] * lsp[0];
    const float invs = 0.08838834764831845f;  // 1/sqrt(128)

    // ===== Phase A: q-pass, sq = sigmoid(q) kept in registers =====
    // layout matches numden acc: n = n0 + s*16 + kg*4 + r, e = w*32 + ct*16 + row
    f32x4 sqa[2][2];
#pragma unroll
    for (int s = 0; s < 2; s++)
#pragma unroll
        for (int ct = 0; ct < 2; ct++) sqa[s][ct] = (f32x4)0.f;
#pragma unroll
    for (int s = 0; s < 2; s++) {
        const float* ap = encl + ((size_t)b * N + n0 + s * 16 + row) * D + kg * 8;
#pragma unroll
        for (int ks = 0; ks < 4; ks++) {
            float4 x0 = *(const float4*)(ap + ks * 32);
            float4 x1 = *(const float4*)(ap + ks * 32 + 4);
            s16x8 ah, al;
            fsplit8(x0, x1, ah, al);
            int wb = ks * 32 + kg * 8;
#pragma unroll
            for (int ct = 0; ct < 2; ct++) {
                int e = w * 32 + ct * 16 + row;
                s16x8 bh = *(const s16x8*)(Wq_hi + e * D + wb);
                s16x8 bl = *(const s16x8*)(Wq_lo + e * D + wb);
                sqa[s][ct] = MFMA16(ah, bh, sqa[s][ct]);
                sqa[s][ct] = MFMA16(al, bh, sqa[s][ct]);
                sqa[s][ct] = MFMA16(ah, bl, sqa[s][ct]);
            }
        }
    }
    float sqv[2][2][4];
#pragma unroll
    for (int s = 0; s < 2; s++)
#pragma unroll
        for (int ct = 0; ct < 2; ct++) {
            int e = w * 32 + ct * 16 + row;
            float wcol = Wq[e * 129 + 128];
#pragma unroll
            for (int r = 0; r < 4; r++) {
                int n = n0 + s * 16 + kg * 4 + r;
                float q = sqa[s][ct][r] + loadv[(size_t)b * N + n] * wcol;
                sqv[s][ct][r] = 1.f / (1.f + __expf(-q));
            }
        }

    // ===== Phase B: num=EB@EKV, den=EB@EK (EB single bf16) =====
    f32x4 accN[2][2], accD[2][2];      // [n-set][ct]
#pragma unroll
    for (int s = 0; s < 2; s++)
#pragma unroll
        for (int i = 0; i < 2; i++) { accN[s][i] = (f32x4)0.f; accD[s][i] = (f32x4)0.f; }
    const char* gEKV = (const char*)EKVb + (size_t)b * D * M * 2;
    const char* gEK  = (const char*)EKb  + (size_t)b * D * M * 2;
    const float* cdp0 = cd + ((size_t)b * N + n0 + row) * M + kg * 8;
    const float* nfp0 = ninf + ((size_t)b * N + n0 + row) * M + kg * 8;
    const float* cdp1 = cdp0 + (size_t)16 * M;
    const float* nfp1 = nfp0 + (size_t)16 * M;
    int rbase = w * 2048 + row * 64 + ((kg ^ (row & 3)) << 4);

#define STAGE_ND(ldsbase, mt)                                                    \
    _Pragma("unroll")                                                            \
    for (int jv = 0; jv < 4; jv++) {                                             \
        int idx = jv * 256 + threadIdx.x;                                        \
        const char* gb = (idx >> 9) ? gEK : gEKV;                                \
        int rem = idx & 511;                                                     \
        gload16(gb + (size_t)(rem >> 2) * 1024 + (size_t)(mt) * 64 + (rem & 3) * 16, \
                (char*)(ldsbase) + idx * 16);                                    \
    }

    float4 c00 = *(const float4*)(cdp0), c01 = *(const float4*)(cdp0 + 4);
    float4 f00 = *(const float4*)(nfp0), f01 = *(const float4*)(nfp0 + 4);
    float4 c10 = *(const float4*)(cdp1), c11 = *(const float4*)(cdp1 + 4);
    float4 f10 = *(const float4*)(nfp1), f11 = *(const float4*)(nfp1 + 4);
    STAGE_ND((char*)lds, 0)

#pragma unroll 2
    for (int mt = 0; mt < 16; mt++) {
        int cur = mt & 1;
        __syncthreads();   // drains stages of buf[cur] (issued a full phase ago)
        s16x8 a0, a1;
        ebpack(c00, c01, f00, f01, a1ls, a0);
        ebpack(c10, c11, f10, f11, a1ls, a1);
        if (mt < 15) {
            int m = (mt + 1) * 32;
            c00 = *(const float4*)(cdp0 + m); c01 = *(const float4*)(cdp0 + m + 4);
            f00 = *(const float4*)(nfp0 + m); f01 = *(const float4*)(nfp0 + m + 4);
            c10 = *(const float4*)(cdp1 + m); c11 = *(const float4*)(cdp1 + m + 4);
            f10 = *(const float4*)(nfp1 + m); f11 = *(const float4*)(nfp1 + m + 4);
            STAGE_ND((char*)lds + (cur ^ 1) * 16384, mt + 1)
        }
        const char* L = (const char*)lds + cur * 16384;
#pragma unroll
        for (int ct = 0; ct < 2; ct++) {
            int ro = ct * 1024 + rbase;
            s16x8 bv = *(const s16x8*)(L + ro);           // EKV bf16
            s16x8 bk = *(const s16x8*)(L + 8192 + ro);    // EK bf16
            accN[0][ct] = MFMA16(a0, bv, accN[0][ct]);
            accN[1][ct] = MFMA16(a1, bv, accN[1][ct]);
            accD[0][ct] = MFMA16(a0, bk, accD[0][ct]);
            accD[1][ct] = MFMA16(a1, bk, accD[1][ct]);
        }
    }

    // ===== Phase C: aafm = sq*nan_to_num(num/den); bounce to score-A layout =====
    float* af = (float*)lds;   // 16 KB region (buf0); last MFMA phase read buf1
#pragma unroll
    for (int s = 0; s < 2; s++)
#pragma unroll
        for (int ct = 0; ct < 2; ct++) {
            int e = w * 32 + ct * 16 + row;
#pragma unroll
            for (int r = 0; r < 4; r++) {
                int nl = s * 16 + kg * 4 + r;
                float num = accN[s][ct][r], den = accD[s][ct][r];
                float ww = (den != 0.f) ? num / den : 0.f;
                float aafm = sqv[s][ct][r] * ww;
                unsigned u = __float_as_uint(aafm);
                unsigned hi = u >> 16;
                float fh = __uint_as_float(u & 0xffff0000u);
                unsigned lo = __float_as_uint(aafm - fh) >> 16;
                af[nl * 128 + e] = __uint_as_float(hi | (lo << 16));
            }
        }
    __syncthreads();
    s16x8 ah[4], al[4];
#pragma unroll
    for (int es = 0; es < 4; es++) {
        const float* src = af + (ng * 16 + row) * 128 + es * 32 + kg * 8;
        float4 w0 = *(const float4*)(src);
        float4 w1 = *(const float4*)(src + 4);
        unsigned u;
        u = __float_as_uint(w0.x); ah[es][0] = (short)(u & 0xffff); al[es][0] = (short)(u >> 16);
        u = __float_as_uint(w0.y); ah[es][1] = (short)(u & 0xffff); al[es][1] = (short)(u >> 16);
        u = __float_as_uint(w0.z); ah[es][2] = (short)(u & 0xffff); al[es][2] = (short)(u >> 16);
        u = __float_as_uint(w0.w); ah[es][3] = (short)(u & 0xffff); al[es][3] = (short)(u >> 16);
        u = __float_as_uint(w1.x); ah[es][4] = (short)(u & 0xffff); al[es][4] = (short)(u >> 16);
        u = __float_as_uint(w1.y); ah[es][5] = (short)(u & 0xffff); al[es][5] = (short)(u >> 16);
        u = __float_as_uint(w1.z); ah[es][6] = (short)(u & 0xffff); al[es][6] = (short)(u >> 16);
        u = __float_as_uint(w1.w); ah[es][7] = (short)(u & 0xffff); al[es][7] = (short)(u >> 16);
    }
    __syncthreads();   // done with af; lds reused for score staging

    // ===== Phase D: score = AAFM@enc^T, bias+tanh+mask, softmax =====
    f32x4 acc[16];
#pragma unroll
    for (int i = 0; i < 16; i++) acc[i] = (f32x4)0.f;
    int mloc = mh * 16 + row;
    int rb2 = mloc * 256;
    int sw = mloc & 7;
    size_t rowidx[4];
#pragma unroll
    for (int r = 0; r < 4; r++)
        rowidx[r] = ((size_t)b * N + n0 + ng * 16 + kg * 4 + r) * M;

#define STAGE_SC(ldsbase, mc)                                                      \
    _Pragma("unroll")                                                              \
    for (int jv = 0; jv < 4; jv++) {                                               \
        int id = (w * 4 + jv) * 64 + lane;                                         \
        int arr = id >> 9, rem = id & 511;                                         \
        const unsigned short* gb = arr ? El : Eh;                                  \
        gload16((const char*)gb + ((size_t)b * M + (size_t)(mc) * 32) * 256 + rem * 16, \
                (char*)(ldsbase) + arr * 8192 + rem * 16);                         \
    }

    STAGE_SC((char*)lds, 0)
#pragma unroll
    for (int mc = 0; mc < 16; mc++) {
        int cur = mc & 1;
        __syncthreads();   // drains stages of buf[cur]
        const char* L = (const char*)lds + cur * 16384;
#pragma unroll
        for (int es = 0; es < 4; es++) {
            int ph = (4 * es + kg) ^ sw;
            s16x8 bh = *(const s16x8*)(L + rb2 + ph * 16);
            s16x8 bl = *(const s16x8*)(L + 8192 + rb2 + ph * 16);
            acc[mc] = MFMA16(ah[es], bh, acc[mc]);
            acc[mc] = MFMA16(al[es], bh, acc[mc]);
            acc[mc] = MFMA16(ah[es], bl, acc[mc]);
        }
        // this tile's cd/ninf (L2-hot: same block read them in phase B)
        float cdv[4], nfv[4];
#pragma unroll
        for (int r = 0; r < 4; r++) {
            size_t idx = rowidx[r] + (size_t)mc * 32 + mloc;
            cdv[r] = cd[idx];
            nfv[r] = ninf[idx];
        }
        if (mc < 15) STAGE_SC((char*)lds + (cur ^ 1) * 16384, mc + 1)
#pragma unroll
        for (int r = 0; r < 4; r++) {
            acc[mc][r] = 10.f * fast_tanh(fmaf(acc[mc][r], invs, -a2ls * cdv[r]))
                       + nfv[r];
        }
    }
    // softmax over m (cross-wave via mh halves)
    float mx[4], sm[4];
#pragma unroll
    for (int r = 0; r < 4; r++) {
        float m = acc[0][r];
#pragma unroll
        for (int a = 1; a < 16; a++) m = fmaxf(m, acc[a][r]);
#pragma unroll
        for (int s = 1; s < 16; s <<= 1) m = fmaxf(m, __shfl_xor(m, s, 64));
        mx[r] = m;
    }
    int rl = ng * 16 + kg * 4;
    if (row == 0) {
#pragma unroll
        for (int r = 0; r < 4; r++) redm[rl + r][mh] = mx[r];
    }
    __syncthreads();
#pragma unroll
    for (int r = 0; r < 4; r++) {
        float m = fmaxf(redm[rl + r][0], redm[rl + r][1]);
        float s = 0.f;
#pragma unroll
        for (int a = 0; a < 16; a++) {
            float e = __expf(acc[a][r] - m);
            acc[a][r] = e;
            s += e;
        }
#pragma unroll
        for (int sh = 1; sh < 16; sh <<= 1) s += __shfl_xor(s, sh, 64);
        sm[r] = s;
    }
    if (row == 0) {
#pragma unroll
        for (int r = 0; r < 4; r++) reds[rl + r][mh] = sm[r];
    }
    __syncthreads();
#pragma unroll
    for (int r = 0; r < 4; r++) {
        float inv = 1.f / (reds[rl + r][0] + reds[rl + r][1]);
        size_t ro = ((size_t)b * N + n0 + rl + r) * M;
#pragma unroll
        for (int a = 0; a < 16; a++) {
            out[ro + a * 32 + mh * 16 + row] = acc[a][r] * inv;
        }
    }
}

extern "C" void kernel_launch(void* const* d_in, const int* in_sizes, int n_in,
                              void* d_out, int out_size, void* d_ws, size_t ws_size,
                              hipStream_t stream) {
    const float* encl  = (const float*)d_in[0];
    const float* loadv = (const float*)d_in[1];
    const float* cdist = (const float*)d_in[2];
    const float* ls    = (const float*)d_in[3];
    const float* ninf  = (const float*)d_in[4];
    const float* enc   = (const float*)d_in[5];
    const float* Wq    = (const float*)d_in[6];
    const float* Wk    = (const float*)d_in[7];
    const float* Wv    = (const float*)d_in[8];
    const float* a1    = (const float*)d_in[9];
    const float* a2    = (const float*)d_in[10];
    char* ws = (char*)d_ws;
    unsigned short* EKb     = (unsigned short*)(ws);                    // 16.8 MB
    unsigned short* EKVb    = (unsigned short*)(ws + 16777216);         // 16.8 MB
    unsigned short* ENC_hi  = (unsigned short*)(ws + 33554432);         // 16.8 MB
    unsigned short* ENC_lo  = (unsigned short*)(ws + 50331648);         // 16.8 MB
    unsigned short* Wk_hi   = (unsigned short*)(ws + 67108864);
    unsigned short* Wk_lo   = (unsigned short*)(ws + 67108864 + 32768);
    unsigned short* Wv_hi   = (unsigned short*)(ws + 67108864 + 65536);
    unsigned short* Wv_lo   = (unsigned short*)(ws + 67108864 + 98304);
    unsigned short* Wq_hi   = (unsigned short*)(ws + 67108864 + 131072);
    unsigned short* Wq_lo   = (unsigned short*)(ws + 67108864 + 163840);
    float* out = (float*)d_out;

    k_prep_w<<<192, 256, 0, stream>>>(Wk, Wv, Wq, Wk_hi, Wk_lo, Wv_hi, Wv_lo, Wq_hi, Wq_lo);
    k_kv<<<dim3(8, 128), 256, 0, stream>>>(enc, Wk_hi, Wk_lo, Wv_hi, Wv_lo, EKb, EKVb);
    k_encsplit<<<4096, 256, 0, stream>>>(enc, ENC_hi, ENC_lo);
    k_fused<<<2048, 256, 0, stream>>>(encl, loadv, Wq, Wq_hi, Wq_lo,
                                      cdist, ninf, EKVb, EKb, ENC_hi, ENC_lo,
                                      a1, a2, ls, out);
}

// Round 12
// 350.857 us; speedup vs baseline: 1.1710x; 1.0349x over previous
//
#include <hip/hip_runtime.h>
#include <math.h>

#define B 128
#define N 512
#define M 512
#define D 128

typedef __attribute__((ext_vector_type(8))) short s16x8;
typedef __attribute__((ext_vector_type(4))) short s16x4;
typedef __attribute__((ext_vector_type(4))) float f32x4;

#define MFMA16(a, b, c) __builtin_amdgcn_mfma_f32_16x16x32_bf16(a, b, c, 0, 0, 0)

#define FENCE()   asm volatile("" ::: "memory")
#define VMCNT4()  asm volatile("s_waitcnt vmcnt(4)" ::: "memory")
#define VMCNT8()  asm volatile("s_waitcnt vmcnt(8)" ::: "memory")
#define VMCNT12() asm volatile("s_waitcnt vmcnt(12)" ::: "memory")
#define VMCNT20() asm volatile("s_waitcnt vmcnt(20)" ::: "memory")
#define LGKMCNT0() asm volatile("s_waitcnt lgkmcnt(0)" ::: "memory")
#define SCHEDBAR() __builtin_amdgcn_sched_barrier(0)

__device__ __forceinline__ void gload16(const void* g, void* l) {
    __builtin_amdgcn_global_load_lds(
        (const __attribute__((address_space(1))) unsigned int*)g,
        (__attribute__((address_space(3))) unsigned int*)l, 16, 0, 0);
}

__device__ __forceinline__ float fast_tanh(float x) {
    x = fminf(fmaxf(x, -15.f), 15.f);
    float E = __expf(2.f * x);
    return 1.f - 2.f / (E + 1.f);
}

__device__ __forceinline__ unsigned short bf16rne(float x) {
    unsigned u = __float_as_uint(x);
    return (unsigned short)((u + 0x7FFF + ((u >> 16) & 1)) >> 16);
}

__device__ __forceinline__ void fsplit(float x, short& h, short& l) {
    unsigned u = __float_as_uint(x);
    h = (short)(u >> 16);
    float fh = __uint_as_float(u & 0xffff0000u);
    l = (short)(__float_as_uint(x - fh) >> 16);
}

__device__ __forceinline__ void fsplit8(float4 x0, float4 x1, s16x8& h, s16x8& l) {
    short a, b;
    fsplit(x0.x, a, b); h[0] = a; l[0] = b;
    fsplit(x0.y, a, b); h[1] = a; l[1] = b;
    fsplit(x0.z, a, b); h[2] = a; l[2] = b;
    fsplit(x0.w, a, b); h[3] = a; l[3] = b;
    fsplit(x1.x, a, b); h[4] = a; l[4] = b;
    fsplit(x1.y, a, b); h[5] = a; l[5] = b;
    fsplit(x1.z, a, b); h[6] = a; l[6] = b;
    fsplit(x1.w, a, b); h[7] = a; l[7] = b;
}

// EB = exp(-a1ls*cd + ninf) -> single bf16 RNE
__device__ __forceinline__ void ebpack(float4 c0, float4 c1, float4 f0, float4 f1,
                                       float a1ls, s16x8& a) {
    a[0] = (short)bf16rne(__expf(fmaf(-a1ls, c0.x, f0.x)));
    a[1] = (short)bf16rne(__expf(fmaf(-a1ls, c0.y, f0.y)));
    a[2] = (short)bf16rne(__expf(fmaf(-a1ls, c0.z, f0.z)));
    a[3] = (short)bf16rne(__expf(fmaf(-a1ls, c0.w, f0.w)));
    a[4] = (short)bf16rne(__expf(fmaf(-a1ls, c1.x, f1.x)));
    a[5] = (short)bf16rne(__expf(fmaf(-a1ls, c1.y, f1.y)));
    a[6] = (short)bf16rne(__expf(fmaf(-a1ls, c1.z, f1.z)));
    a[7] = (short)bf16rne(__expf(fmaf(-a1ls, c1.w, f1.w)));
}

__global__ void k_prep_w(const float* __restrict__ Wk, const float* __restrict__ Wv,
                         const float* __restrict__ Wq,
                         unsigned short* __restrict__ Wk_hi, unsigned short* __restrict__ Wk_lo,
                         unsigned short* __restrict__ Wv_hi, unsigned short* __restrict__ Wv_lo,
                         unsigned short* __restrict__ Wq_hi, unsigned short* __restrict__ Wq_lo) {
    int i = blockIdx.x * 256 + threadIdx.x;  // 0..49151
    short h, l;
    if (i < 16384) {
        fsplit(Wk[i], h, l); Wk_hi[i] = (unsigned short)h; Wk_lo[i] = (unsigned short)l;
    } else if (i < 32768) {
        int j = i - 16384;
        fsplit(Wv[j], h, l); Wv_hi[j] = (unsigned short)h; Wv_lo[j] = (unsigned short)l;
    } else {
        int j = i - 32768; int e = j >> 7, d = j & 127;
        fsplit(Wq[e * 129 + d], h, l); Wq_hi[j] = (unsigned short)h; Wq_lo[j] = (unsigned short)l;
    }
}

// k = enc@Wk^T, v = enc@Wv^T; store bf16-RNE EK, EK*V as [b][e][m],
// SWIZZLED: within each 32-m group, 8-m chunk c stored at c ^ (e&3).
__global__ __launch_bounds__(256) void k_kv(const float* __restrict__ enc,
        const unsigned short* __restrict__ Wk_hi, const unsigned short* __restrict__ Wk_lo,
        const unsigned short* __restrict__ Wv_hi, const unsigned short* __restrict__ Wv_lo,
        unsigned short* __restrict__ EKb, unsigned short* __restrict__ EKVb) {
    int b = blockIdx.y;
    int wave = threadIdx.x >> 6, lane = threadIdx.x & 63;
    int row = lane & 15, kg = lane >> 4;
    int m0 = blockIdx.x * 64 + wave * 16;
    f32x4 acc[16];
#pragma unroll
    for (int i = 0; i < 16; i++) acc[i] = (f32x4)0.f;
    const float* ap = enc + ((size_t)b * M + m0 + row) * D + kg * 8;
#pragma unroll
    for (int ks = 0; ks < 4; ks++) {
        float4 x0 = *(const float4*)(ap + ks * 32);
        float4 x1 = *(const float4*)(ap + ks * 32 + 4);
        s16x8 ah, al;
        fsplit8(x0, x1, ah, al);
        int wb = ks * 32 + kg * 8;
#pragma unroll
        for (int ct = 0; ct < 8; ct++) {
            int e = ct * 16 + row;
            s16x8 bh = *(const s16x8*)(Wk_hi + e * D + wb);
            s16x8 bl = *(const s16x8*)(Wk_lo + e * D + wb);
            acc[ct] = MFMA16(ah, bh, acc[ct]);
            acc[ct] = MFMA16(al, bh, acc[ct]);
            acc[ct] = MFMA16(ah, bl, acc[ct]);
            bh = *(const s16x8*)(Wv_hi + e * D + wb);
            bl = *(const s16x8*)(Wv_lo + e * D + wb);
            acc[8 + ct] = MFMA16(ah, bh, acc[8 + ct]);
            acc[8 + ct] = MFMA16(al, bh, acc[8 + ct]);
            acc[8 + ct] = MFMA16(ah, bl, acc[8 + ct]);
        }
    }
#pragma unroll
    for (int ct = 0; ct < 8; ct++) {
        int e = ct * 16 + row;
        s16x4 kb, vb;
#pragma unroll
        for (int r = 0; r < 4; r++) {
            float ek = __expf(acc[ct][r]);
            float ev = ek * acc[8 + ct][r];
            kb[r] = (short)bf16rne(ek);
            vb[r] = (short)bf16rne(ev);
        }
        int m = m0 + kg * 4;
        int chunk = (m & 31) >> 3;
        int p = chunk ^ (e & 3);
        size_t o = ((size_t)b * D + e) * M + (size_t)(m & ~31) + p * 8 + (m & 7);
        *(s16x4*)(EKb + o) = kb;
        *(s16x4*)(EKVb + o) = vb;
    }
}

// Pack enc -> single bf16-RNE [b][m][128e], SWIZZLED: 8-e chunk c at c ^ (m&7)
__global__ void k_encpack(const float* __restrict__ enc, unsigned short* __restrict__ Eb) {
    size_t i = (size_t)blockIdx.x * 256 + threadIdx.x;   // chunk id
    size_t bm = i >> 4;
    int c = (int)(i & 15);
    int m = (int)(bm & 511);
    int p = c ^ (m & 7);
    const float* src = enc + bm * 128 + c * 8;
    float4 x0 = *(const float4*)(src);
    float4 x1 = *(const float4*)(src + 4);
    s16x8 v;
    v[0] = (short)bf16rne(x0.x); v[1] = (short)bf16rne(x0.y);
    v[2] = (short)bf16rne(x0.z); v[3] = (short)bf16rne(x0.w);
    v[4] = (short)bf16rne(x1.x); v[5] = (short)bf16rne(x1.y);
    v[6] = (short)bf16rne(x1.z); v[7] = (short)bf16rne(x1.w);
    *(s16x8*)(Eb + bm * 128 + p * 8) = v;
}

// MEGA-FUSED, BARRIER-FREE MAIN LOOPS: q + numden + aafm + score + softmax.
// Wave-private LDS staging; per-wave vmcnt sync only. Grid 2048 XCD-bijective.
__global__ __launch_bounds__(256, 3) void k_fused(
        const float* __restrict__ encl, const float* __restrict__ loadv,
        const float* __restrict__ Wq,
        const unsigned short* __restrict__ Wq_hi, const unsigned short* __restrict__ Wq_lo,
        const float* __restrict__ cd, const float* __restrict__ ninf,
        const unsigned short* __restrict__ EKVb, const unsigned short* __restrict__ EKb,
        const unsigned short* __restrict__ Eb,
        const float* __restrict__ a1p, const float* __restrict__ a2p,
        const float* __restrict__ lsp, float* __restrict__ out) {
    int o = blockIdx.x;
    int xcd = o & 7, j = o >> 3;       // j 0..255
    int b = ((j >> 4) << 3) + xcd;     // 16 b's per XCD
    int nb = j & 15;
    int n0 = nb * 32;
    int w = threadIdx.x >> 6, lane = threadIdx.x & 63;
    int row = lane & 15, kg = lane >> 4;
    __shared__ __align__(16) char lds[32768];   // wave-private: wave w owns [w*8K, +8K)
    __shared__ float redm[32][4], reds[32][4];
    float a1ls = a1p[0] * lsp[0];
    float a2ls = a2p[0] * lsp[0];
    const float invs = 0.08838834764831845f;  // 1/sqrt(128)
    char* wb = lds + w * 8192;                // 2 bufs x 4 KB

    // ===== Phase A: q-pass; sq = sigmoid(q) in regs (e = w*32 + ct*16 + row) =====
    f32x4 sqa[2][2];
#pragma unroll
    for (int s = 0; s < 2; s++)
#pragma unroll
        for (int ct = 0; ct < 2; ct++) sqa[s][ct] = (f32x4)0.f;
#pragma unroll
    for (int s = 0; s < 2; s++) {
        const float* ap = encl + ((size_t)b * N + n0 + s * 16 + row) * D + kg * 8;
#pragma unroll
        for (int ks = 0; ks < 4; ks++) {
            float4 x0 = *(const float4*)(ap + ks * 32);
            float4 x1 = *(const float4*)(ap + ks * 32 + 4);
            s16x8 ah, al;
            fsplit8(x0, x1, ah, al);
            int wqo = ks * 32 + kg * 8;
#pragma unroll
            for (int ct = 0; ct < 2; ct++) {
                int e = w * 32 + ct * 16 + row;
                s16x8 bh = *(const s16x8*)(Wq_hi + e * D + wqo);
                s16x8 bl = *(const s16x8*)(Wq_lo + e * D + wqo);
                sqa[s][ct] = MFMA16(ah, bh, sqa[s][ct]);
                sqa[s][ct] = MFMA16(al, bh, sqa[s][ct]);
                sqa[s][ct] = MFMA16(ah, bl, sqa[s][ct]);
            }
        }
    }
    float sqv[2][2][4];
#pragma unroll
    for (int s = 0; s < 2; s++)
#pragma unroll
        for (int ct = 0; ct < 2; ct++) {
            int e = w * 32 + ct * 16 + row;
            float wcol = Wq[e * 129 + 128];
#pragma unroll
            for (int r = 0; r < 4; r++) {
                int n = n0 + s * 16 + kg * 4 + r;
                float q = sqa[s][ct][r] + loadv[(size_t)b * N + n] * wcol;
                sqv[s][ct][r] = 1.f / (1.f + __expf(-q));
            }
        }
    FENCE();   // pin all phase-A vmem before the B ledger starts

    // ===== Phase B: num/den, wave-private e-slice [w*32, w*32+32) =====
    f32x4 accN[2][2], accD[2][2];
#pragma unroll
    for (int s = 0; s < 2; s++)
#pragma unroll
        for (int i = 0; i < 2; i++) { accN[s][i] = (f32x4)0.f; accD[s][i] = (f32x4)0.f; }
    const char* gEKV = (const char*)EKVb + (size_t)b * D * M * 2;
    const char* gEK  = (const char*)EKb  + (size_t)b * D * M * 2;
    const float* cdp0 = cd + ((size_t)b * N + n0 + row) * M + kg * 8;
    const float* nfp0 = ninf + ((size_t)b * N + n0 + row) * M + kg * 8;
    const float* cdp1 = cdp0 + (size_t)16 * M;
    const float* nfp1 = nfp0 + (size_t)16 * M;

// stage wave's 4 KB slice of tile mt into bufptr: [2 arr][32 e][64 B]
#define STAGE_B(bufptr, mt)                                                      \
    _Pragma("unroll")                                                            \
    for (int jv = 0; jv < 4; jv++) {                                             \
        int arr = jv >> 1;                                                       \
        int rem = (jv & 1) * 64 + lane;                                          \
        const char* gb = arr ? gEK : gEKV;                                       \
        gload16(gb + (size_t)(w * 32 + (rem >> 2)) * 1024 + (size_t)(mt) * 64 +  \
                    (rem & 3) * 16,                                              \
                (char*)(bufptr) + arr * 2048 + rem * 16);                        \
    }

    float4 Ac[2][2][2], Af[2][2][2];   // [parity][n-set][half]
#define LOAD_A(p, mt)                                                            \
    Ac[p][0][0] = *(const float4*)(cdp0 + (mt) * 32);                            \
    Ac[p][0][1] = *(const float4*)(cdp0 + (mt) * 32 + 4);                        \
    Af[p][0][0] = *(const float4*)(nfp0 + (mt) * 32);                            \
    Af[p][0][1] = *(const float4*)(nfp0 + (mt) * 32 + 4);                        \
    Ac[p][1][0] = *(const float4*)(cdp1 + (mt) * 32);                            \
    Ac[p][1][1] = *(const float4*)(cdp1 + (mt) * 32 + 4);                        \
    Af[p][1][0] = *(const float4*)(nfp1 + (mt) * 32);                            \
    Af[p][1][1] = *(const float4*)(nfp1 + (mt) * 32 + 4);

    // prologue order (fenced): A0, S0, A1, S1
    LOAD_A(0, 0) FENCE();
    STAGE_B(wb, 0) FENCE();
    LOAD_A(1, 1) FENCE();
    STAGE_B(wb + 4096, 1) FENCE();

    int rbB = row * 64 + ((kg ^ (row & 3)) << 4);
#pragma unroll
    for (int mt = 0; mt < 16; mt++) {
        // W(t): younger-than-S(t) = {t<2: A(t^1)+S(t^1) = 12 ; 2..14: A(t)+S(t+1)+A(t+1) = 20 ; 15: A(15) = 8}
        if (mt < 2) { VMCNT12(); } else if (mt < 15) { VMCNT20(); } else { VMCNT8(); }
        SCHEDBAR();
        int p = mt & 1;
        s16x8 a0, a1;
        ebpack(Ac[p][0][0], Ac[p][0][1], Af[p][0][0], Af[p][0][1], a1ls, a0);
        ebpack(Ac[p][1][0], Ac[p][1][1], Af[p][1][0], Af[p][1][1], a1ls, a1);
        const char* L = wb + p * 4096;
#pragma unroll
        for (int ct = 0; ct < 2; ct++) {
            int ro = ct * 1024 + rbB;
            s16x8 bv = *(const s16x8*)(L + ro);           // EKV
            s16x8 bk = *(const s16x8*)(L + 2048 + ro);    // EK
            accN[0][ct] = MFMA16(a0, bv, accN[0][ct]);
            accN[1][ct] = MFMA16(a1, bv, accN[1][ct]);
            accD[0][ct] = MFMA16(a0, bk, accD[0][ct]);
            accD[1][ct] = MFMA16(a1, bk, accD[1][ct]);
        }
        if (mt <= 13) {
            LGKMCNT0();   // own ds_reads of this buffer done -> safe to restage
            SCHEDBAR();
            STAGE_B(wb + p * 4096, mt + 2) FENCE();
            LOAD_A(p, mt + 2) FENCE();
        }
    }

    // ===== Phase C: aafm bounce (block-shared -> needs barriers) =====
    __syncthreads();   // all waves done with B buffers
    float* af = (float*)lds;   // 16 KB: [32 n][128 e] packed hi|lo<<16
#pragma unroll
    for (int s = 0; s < 2; s++)
#pragma unroll
        for (int ct = 0; ct < 2; ct++) {
            int e = w * 32 + ct * 16 + row;
#pragma unroll
            for (int r = 0; r < 4; r++) {
                int nl = s * 16 + kg * 4 + r;
                float num = accN[s][ct][r], den = accD[s][ct][r];
                float ww = (den != 0.f) ? num / den : 0.f;
                float aafm = sqv[s][ct][r] * ww;
                unsigned u = __float_as_uint(aafm);
                unsigned hi = u >> 16;
                float fh = __uint_as_float(u & 0xffff0000u);
                unsigned lo = __float_as_uint(aafm - fh) >> 16;
                af[nl * 128 + e] = __uint_as_float(hi | (lo << 16));
            }
        }
    __syncthreads();
    s16x8 ah[2][4], al[2][4];   // A-frags for score: [n-set][es]
#pragma unroll
    for (int s = 0; s < 2; s++)
#pragma unroll
        for (int es = 0; es < 4; es++) {
            const float* src = af + (s * 16 + row) * 128 + es * 32 + kg * 8;
            float4 w0 = *(const float4*)(src);
            float4 w1 = *(const float4*)(src + 4);
            unsigned u;
            u = __float_as_uint(w0.x); ah[s][es][0] = (short)(u & 0xffff); al[s][es][0] = (short)(u >> 16);
            u = __float_as_uint(w0.y); ah[s][es][1] = (short)(u & 0xffff); al[s][es][1] = (short)(u >> 16);
            u = __float_as_uint(w0.z); ah[s][es][2] = (short)(u & 0xffff); al[s][es][2] = (short)(u >> 16);
            u = __float_as_uint(w0.w); ah[s][es][3] = (short)(u & 0xffff); al[s][es][3] = (short)(u >> 16);
            u = __float_as_uint(w1.x); ah[s][es][4] = (short)(u & 0xffff); al[s][es][4] = (short)(u >> 16);
            u = __float_as_uint(w1.y); ah[s][es][5] = (short)(u & 0xffff); al[s][es][5] = (short)(u >> 16);
            u = __float_as_uint(w1.z); ah[s][es][6] = (short)(u & 0xffff); al[s][es][6] = (short)(u >> 16);
            u = __float_as_uint(w1.w); ah[s][es][7] = (short)(u & 0xffff); al[s][es][7] = (short)(u >> 16);
        }
    __syncthreads();   // af dead; lds region reused by wave-private D staging
    FENCE();

    // ===== Phase D: score, wave-private m-quarter [w*128, w*128+128) =====
    // acc[s][p]: n = n0 + s*16 + kg*4 + r ; m = w*128 + p*16 + row
    f32x4 acc[2][8];
#pragma unroll
    for (int s = 0; s < 2; s++)
#pragma unroll
        for (int p = 0; p < 8; p++) acc[s][p] = (f32x4)0.f;
    const char* gEb = (const char*)Eb + (size_t)b * M * 256;

// stage wave's 4 KB (16 m x 256 B) of tile p into bufptr
#define STAGE_D(bufptr, p)                                                       \
    _Pragma("unroll")                                                            \
    for (int jv = 0; jv < 4; jv++) {                                             \
        int id = jv * 64 + lane;                                                 \
        gload16(gEb + (size_t)(w * 128 + (p) * 16 + (id >> 4)) * 256 + (id & 15) * 16, \
                (char*)(bufptr) + id * 16);                                      \
    }

    // prologue (fenced): S0, S1; A loads are depth-1 in-loop (cd/ninf L2-hot)
    STAGE_D(wb, 0) FENCE();
    STAGE_D(wb + 4096, 1) FENCE();

#pragma unroll
    for (int p = 0; p < 8; p++) {
        // W(p): younger-than-S(p) = {0: S1 = 4 ; 1..6: A(p-1)+S(p+1) = 12 ; 7: A(6) = 8}
        if (p == 0) { VMCNT4(); } else if (p < 7) { VMCNT12(); } else { VMCNT8(); }
        SCHEDBAR();
        // this phase's cd/ninf (L2-hot from phase B) — used after MFMA
        float cdv[2][4], nfv[2][4];
#pragma unroll
        for (int s = 0; s < 2; s++)
#pragma unroll
            for (int r = 0; r < 4; r++) {
                size_t idx = ((size_t)b * N + n0 + s * 16 + kg * 4 + r) * M
                           + (size_t)w * 128 + (size_t)p * 16 + row;
                cdv[s][r] = cd[idx];
                nfv[s][r] = ninf[idx];
            }
        FENCE();
        const char* L = wb + (p & 1) * 4096;
        int sw = row & 7;
#pragma unroll
        for (int es = 0; es < 4; es++) {
            int ph = (4 * es + kg) ^ sw;
            s16x8 bb = *(const s16x8*)(L + row * 256 + ph * 16);
            acc[0][p] = MFMA16(ah[0][es], bb, acc[0][p]);
            acc[0][p] = MFMA16(al[0][es], bb, acc[0][p]);
            acc[1][p] = MFMA16(ah[1][es], bb, acc[1][p]);
            acc[1][p] = MFMA16(al[1][es], bb, acc[1][p]);
        }
        if (p <= 5) {
            LGKMCNT0();
            SCHEDBAR();
            STAGE_D(wb + (p & 1) * 4096, p + 2) FENCE();
        }
        // bias + tanh + mask
#pragma unroll
        for (int s = 0; s < 2; s++)
#pragma unroll
            for (int r = 0; r < 4; r++) {
                acc[s][p][r] = 10.f * fast_tanh(fmaf(acc[s][p][r], invs, -a2ls * cdv[s][r]))
                             + nfv[s][r];
            }
    }

    // ===== softmax over m (in-lane p, row-lanes, then 4 wave quarters) =====
    float mx[2][4], sm[2][4];
#pragma unroll
    for (int s = 0; s < 2; s++)
#pragma unroll
        for (int r = 0; r < 4; r++) {
            float m = acc[s][0][r];
#pragma unroll
            for (int p = 1; p < 8; p++) m = fmaxf(m, acc[s][p][r]);
#pragma unroll
            for (int sh = 1; sh < 16; sh <<= 1) m = fmaxf(m, __shfl_xor(m, sh, 64));
            mx[s][r] = m;
        }
    if (row == 0) {
#pragma unroll
        for (int s = 0; s < 2; s++)
#pragma unroll
            for (int r = 0; r < 4; r++) redm[s * 16 + kg * 4 + r][w] = mx[s][r];
    }
    __syncthreads();
#pragma unroll
    for (int s = 0; s < 2; s++)
#pragma unroll
        for (int r = 0; r < 4; r++) {
            int nl = s * 16 + kg * 4 + r;
            float m = fmaxf(fmaxf(redm[nl][0], redm[nl][1]),
                            fmaxf(redm[nl][2], redm[nl][3]));
            float sum = 0.f;
#pragma unroll
            for (int p = 0; p < 8; p++) {
                float e = __expf(acc[s][p][r] - m);
                acc[s][p][r] = e;
                sum += e;
            }
#pragma unroll
            for (int sh = 1; sh < 16; sh <<= 1) sum += __shfl_xor(sum, sh, 64);
            sm[s][r] = sum;
        }
    if (row == 0) {
#pragma unroll
        for (int s = 0; s < 2; s++)
#pragma unroll
            for (int r = 0; r < 4; r++) reds[s * 16 + kg * 4 + r][w] = sm[s][r];
    }
    __syncthreads();
#pragma unroll
    for (int s = 0; s < 2; s++)
#pragma unroll
        for (int r = 0; r < 4; r++) {
            int nl = s * 16 + kg * 4 + r;
            float inv = 1.f / (reds[nl][0] + reds[nl][1] + reds[nl][2] + reds[nl][3]);
            size_t ro = ((size_t)b * N + n0 + nl) * M + (size_t)w * 128 + row;
#pragma unroll
            for (int p = 0; p < 8; p++) {
                out[ro + p * 16] = acc[s][p][r] * inv;
            }
        }
}

extern "C" void kernel_launch(void* const* d_in, const int* in_sizes, int n_in,
                              void* d_out, int out_size, void* d_ws, size_t ws_size,
                              hipStream_t stream) {
    const float* encl  = (const float*)d_in[0];
    const float* loadv = (const float*)d_in[1];
    const float* cdist = (const float*)d_in[2];
    const float* ls    = (const float*)d_in[3];
    const float* ninf  = (const float*)d_in[4];
    const float* enc   = (const float*)d_in[5];
    const float* Wq    = (const float*)d_in[6];
    const float* Wk    = (const float*)d_in[7];
    const float* Wv    = (const float*)d_in[8];
    const float* a1    = (const float*)d_in[9];
    const float* a2    = (const float*)d_in[10];
    char* ws = (char*)d_ws;
    unsigned short* EKb     = (unsigned short*)(ws);                    // 16.8 MB
    unsigned short* EKVb    = (unsigned short*)(ws + 16777216);         // 16.8 MB
    unsigned short* Eb      = (unsigned short*)(ws + 33554432);         // 16.8 MB
    unsigned short* Wk_hi   = (unsigned short*)(ws + 50331648);
    unsigned short* Wk_lo   = (unsigned short*)(ws + 50331648 + 32768);
    unsigned short* Wv_hi   = (unsigned short*)(ws + 50331648 + 65536);
    unsigned short* Wv_lo   = (unsigned short*)(ws + 50331648 + 98304);
    unsigned short* Wq_hi   = (unsigned short*)(ws + 50331648 + 131072);
    unsigned short* Wq_lo   = (unsigned short*)(ws + 50331648 + 163840);
    float* out = (float*)d_out;

    k_prep_w<<<192, 256, 0, stream>>>(Wk, Wv, Wq, Wk_hi, Wk_lo, Wv_hi, Wv_lo, Wq_hi, Wq_lo);
    k_kv<<<dim3(8, 128), 256, 0, stream>>>(enc, Wk_hi, Wk_lo, Wv_hi, Wv_lo, EKb, EKVb);
    k_encpack<<<4096, 256, 0, stream>>>(enc, Eb);
    k_fused<<<2048, 256, 0, stream>>>(encl, loadv, Wq, Wq_hi, Wq_lo,
                                      cdist, ninf, EKVb, EKb, Eb,
                                      a1, a2, ls, out);
}